// Round 7
// baseline (579.427 us; speedup 1.0000x reference)
//
#include <hip/hip_runtime.h>

#define TOK 4096
#define NE 16
#define HD 2048
#define ID 1024
#define QGROUP 16
#define CAP 4096

typedef _Float16 half4v __attribute__((ext_vector_type(4)));
typedef _Float16 half8v __attribute__((ext_vector_type(8)));
typedef float float4v __attribute__((ext_vector_type(4)));

__device__ __forceinline__ void g2l16(const void* g, void* l) {
    __builtin_amdgcn_global_load_lds(
        (const __attribute__((address_space(1))) unsigned int*)g,
        (__attribute__((address_space(3))) unsigned int*)l, 16, 0, 0);
}

// ---------------- router: per-token top2 + fused f32->f16 conversion of x ----------------
__global__ __launch_bounds__(256) void router_kernel(
    const float* __restrict__ x, const float* __restrict__ gw,
    _Float16* __restrict__ xh, int* __restrict__ topi, float* __restrict__ topw)
{
    const int t = blockIdx.x;
    const int tid = threadIdx.x;
    const int h8 = tid * 8;
    const float* xr = x + (size_t)t * HD;
    const float4 f0 = *(const float4*)&xr[h8];
    const float4 f1 = *(const float4*)&xr[h8 + 4];
    half8v hv;
    hv[0] = (_Float16)f0.x; hv[1] = (_Float16)f0.y; hv[2] = (_Float16)f0.z; hv[3] = (_Float16)f0.w;
    hv[4] = (_Float16)f1.x; hv[5] = (_Float16)f1.y; hv[6] = (_Float16)f1.z; hv[7] = (_Float16)f1.w;
    *(half8v*)&xh[(size_t)t * HD + h8] = hv;

    float p[NE];
#pragma unroll
    for (int e = 0; e < NE; e++) {
        const float4 g0 = *(const float4*)&gw[e * HD + h8];
        const float4 g1 = *(const float4*)&gw[e * HD + h8 + 4];
        p[e] = f0.x * g0.x + f0.y * g0.y + f0.z * g0.z + f0.w * g0.w
             + f1.x * g1.x + f1.y * g1.y + f1.z * g1.z + f1.w * g1.w;
    }
#pragma unroll
    for (int off = 32; off > 0; off >>= 1) {
#pragma unroll
        for (int e = 0; e < NE; e++) p[e] += __shfl_down(p[e], off, 64);
    }
    __shared__ float part[4][NE];
    int wave = tid >> 6, lane = tid & 63;
    if (lane == 0) {
#pragma unroll
        for (int e = 0; e < NE; e++) part[wave][e] = p[e];
    }
    __syncthreads();
    if (tid == 0) {
        float s[NE]; float sum = 0.f;
#pragma unroll
        for (int e = 0; e < NE; e++) {
            float l = part[0][e] + part[1][e] + part[2][e] + part[3][e];
            float sg = 1.f / (1.f + expf(-l));
            s[e] = sg; sum += sg;
        }
        int i1 = 0;
#pragma unroll
        for (int e = 1; e < NE; e++) if (s[e] > s[i1]) i1 = e;
        int i2 = (i1 == 0) ? 1 : 0;
#pragma unroll
        for (int e = 0; e < NE; e++) if (e != i1 && s[e] > s[i2]) i2 = e;
        float p1 = s[i1] / sum, p2 = s[i2] / sum;
        float inv = 1.f / (p1 + p2 + 1e-20f);
        topi[t * 2 + 0] = i1; topw[t * 2 + 0] = p1 * inv;
        topi[t * 2 + 1] = i2; topw[t * 2 + 1] = p2 * inv;
    }
}

// ---------------- compaction: one block per expert, deterministic ordered scan ----------------
__global__ __launch_bounds__(256) void compact_kernel(
    const int* __restrict__ topi, const float* __restrict__ topw,
    int* __restrict__ counts, int* __restrict__ pair_row, float* __restrict__ pair_w)
{
    const int e = blockIdx.x;
    const int tid = threadIdx.x;
    const int lane = tid & 63, wv = tid >> 6;
    __shared__ int wsum[4];
    int running = 0;
    for (int base = 0; base < 2 * TOK; base += 256) {
        const int idx = base + tid;
        const bool f = (topi[idx] == e);
        unsigned long long b = __ballot(f);
        int pre = __popcll(b & ((1ull << lane) - 1ull));
        if (lane == 0) wsum[wv] = __popcll(b);
        __syncthreads();
        int woff = 0;
#pragma unroll
        for (int w = 0; w < 4; w++) if (w < wv) woff += wsum[w];
        const int tot = wsum[0] + wsum[1] + wsum[2] + wsum[3];
        if (f) {
            const int pos = running + woff + pre;
            pair_row[e * CAP + pos] = idx;          // pair id = t*2+slot
            pair_w[e * CAP + pos] = topw[idx];
        }
        running += tot;
        __syncthreads();
    }
    if (tid == 0) counts[e] = running;
}

// ---------------- dequant + transpose: codes [E][K][N] int32 -> f16 [E][N][K] ----------------
// LDS tile stride = 70 f16 (35 dwords, odd): transpose-read k-term 35*k mod 32 = {0,16} over
// kseg in {0,16,32,48} -> 2-way (free), vs stride 68 (34 dw, always 0 -> 8-way conflict).
// Writes are 2x u32 (odd-dword stride makes 8B stores misaligned on odd rows; 4B is aligned).
template<int K, int N>
__global__ __launch_bounds__(256) void dequantT_kernel(
    const int* __restrict__ qw, const float* __restrict__ bsc, _Float16* __restrict__ wq)
{
    const int e = blockIdx.z, kt = blockIdx.y, nt = blockIdx.x;
    const int tid = threadIdx.x;
    __shared__ _Float16 T[64][70];   // [k][n]

    const int c4 = (tid & 15) * 4;
    const int r0 = tid >> 4;         // 0..15
#pragma unroll
    for (int p = 0; p < 4; p++) {
        const int r = p * 16 + r0;
        const int kabs = kt * 64 + r;
        const int4 c = *(const int4*)&qw[((size_t)e * K + kabs) * N + nt * 64 + c4];
        const float4 sc = *(const float4*)&bsc[((size_t)e * (K / QGROUP) + (kabs >> 4)) * N + nt * 64 + c4];
        union { _Float16 h[4]; unsigned u[2]; } cv;
        cv.h[0] = (_Float16)((float)(c.x - 8) * sc.x);
        cv.h[1] = (_Float16)((float)(c.y - 8) * sc.y);
        cv.h[2] = (_Float16)((float)(c.z - 8) * sc.z);
        cv.h[3] = (_Float16)((float)(c.w - 8) * sc.w);
        *(unsigned*)&T[r][c4]     = cv.u[0];
        *(unsigned*)&T[r][c4 + 2] = cv.u[1];
    }
    __syncthreads();
    const int nrow = tid >> 2;
    const int kseg = (tid & 3) * 16;
    half8v o0, o1;
#pragma unroll
    for (int i = 0; i < 8; i++) o0[i] = T[kseg + i][nrow];
#pragma unroll
    for (int i = 0; i < 8; i++) o1[i] = T[kseg + 8 + i][nrow];
    _Float16* dst = wq + ((size_t)e * N + nt * 64 + nrow) * K + kt * 64 + kseg;
    *(half8v*)dst = o0;
    *(half8v*)(dst + 8) = o1;
}

// ---------------- gemm5: 256M x 128N x BK=64, XOR-swizzled LDS, 512 threads ----------------
// GEMM is feed-bound on B-panel re-reads (one per M-tile). M-tile 128->256 halves B logical
// traffic (dominant stream: wq 67MB x ceil(cnt/BM) re-reads); per-FLOP feed drops
// 15.6 -> 11.4 B/kFLOP. 8 waves as 4Mx2N, each wave 64x64 (acc 4x4). LDS 98 KB -> 1 block/CU.
// Counted-vmcnt DOUBLE buffer (round-3-verified fence discipline), 6 g2l16/thread/tile:
//   prologue: stage(0->buf0), stage(1->buf1)         [12 loads outstanding]
//   iter it:  s_waitcnt vmcnt(6)  <- tile it landed, tile it+1 flying (vmcnt(0) only at last)
//             s_barrier ; [fence] ; ds_read+MFMA on buf[it&1] ; [fence] ; s_barrier ; [fence]
//             stage(it+2 -> buf[it&1])               [back to 12 outstanding]
// Fences REQUIRED: LLVM models s_barrier as IntrNoMem; without them restage/ds_reads cross
// the raw barrier -> inter-wave WAR race on buf[cur] (round-2 failure mode).
template<int N, int K, bool UP>
__global__ __launch_bounds__(512, 1) void gemm5_kernel(
    const _Float16* __restrict__ A, const _Float16* __restrict__ BT,
    const float* __restrict__ gsc,
    const int* __restrict__ counts, const int* __restrict__ pair_row,
    const float* __restrict__ pair_w,
    _Float16* __restrict__ store16, float* __restrict__ store32)
{
    constexpr int NT = N / 128;
    constexpr int MT = CAP / 256;
    constexpr int NK = K / 64;
    const int bx = blockIdx.x;
    const int g8 = bx & 7;                    // XCD hint
    const int rest = bx >> 3;
    const int m = rest % MT;
    const int g = (rest / MT) * 8 + g8;       // (NT*NE) multiple of 8
    const int e = g / NT, nt = g % NT;
    const int cnt = counts[e];
    const int mbase = m * 256;
    if (mbase >= cnt) return;
    const int nbase = nt * 128;
    const int tid = threadIdx.x;

    __shared__ _Float16 As[2][256 * 64];      // 2 x 32 KB
    __shared__ _Float16 Bs[2][128 * 64];      // 2 x 16 KB
    __shared__ int rows_s[256];
    __shared__ float pw_s[256];

    if (tid < 256) {
        int idx = mbase + tid; if (idx >= cnt) idx = cnt - 1;
        rows_s[tid] = pair_row[e * CAP + idx];
        pw_s[tid] = UP ? pair_w[e * CAP + idx] : 0.f;
    }
    __syncthreads();

    // staging maps (granule = 16 B = 8 f16). A: 2048 granules (4/thread), B: 1024 (2/thread).
    const _Float16* asrc[4]; int aoff[4];
#pragma unroll
    for (int j = 0; j < 4; j++) {
        const int gidx = j * 512 + tid;
        const int r = gidx >> 3, s = gidx & 7, c = s ^ (r & 7);
        const int pr = rows_s[r];
        asrc[j] = A + (size_t)(UP ? (pr >> 1) : pr) * K + c * 8;
        aoff[j] = r * 64 + s * 8;
    }
    const _Float16* bsrc[2]; int boff[2];
#pragma unroll
    for (int j = 0; j < 2; j++) {
        const int gidx = j * 512 + tid;
        const int r = gidx >> 3, s = gidx & 7, c = s ^ (r & 7);
        bsrc[j] = BT + ((size_t)e * N + nbase + r) * K + c * 8;
        boff[j] = r * 64 + s * 8;
    }

    const int lane = tid & 63, wv = tid >> 6;          // wv in [0,8)
    const int quad = lane >> 4, lm = lane & 15;
    const int wr = (wv & 3) * 64, wc = (wv >> 2) * 64; // 4M x 2N wave grid

    float4v acc[4][4];
#pragma unroll
    for (int mi = 0; mi < 4; mi++)
#pragma unroll
        for (int ni = 0; ni < 4; ni++) acc[mi][ni] = (float4v){0.f, 0.f, 0.f, 0.f};

    // prologue: stage tile 0 -> buf0, tile 1 -> buf1 (12 loads in flight)
#pragma unroll
    for (int j = 0; j < 4; j++) g2l16(asrc[j], &As[0][aoff[j]]);
#pragma unroll
    for (int j = 0; j < 2; j++) g2l16(bsrc[j], &Bs[0][boff[j]]);
#pragma unroll
    for (int j = 0; j < 4; j++) g2l16(asrc[j] + 64, &As[1][aoff[j]]);
#pragma unroll
    for (int j = 0; j < 2; j++) g2l16(bsrc[j] + 64, &Bs[1][boff[j]]);

    for (int it = 0; it < NK; ++it) {
        if (it + 1 < NK) {
            asm volatile("s_waitcnt vmcnt(6)" ::: "memory");   // tile it landed; it+1 in flight
        } else {
            asm volatile("s_waitcnt vmcnt(0)" ::: "memory");   // last tile: only its 6 remain
        }
        __builtin_amdgcn_s_barrier();
        asm volatile("" ::: "memory");        // reads must not hoist above barrier1
        const int cur = it & 1;
#pragma unroll
        for (int ks = 0; ks < 2; ks++) {
            half8v af[4], bf[4];
#pragma unroll
            for (int mi = 0; mi < 4; mi++) {
                const int r = wr + mi * 16 + lm;
                const int s = (ks * 4 + quad) ^ (r & 7);
                af[mi] = *(const half8v*)&As[cur][r * 64 + s * 8];
            }
#pragma unroll
            for (int ni = 0; ni < 4; ni++) {
                const int r = wc + ni * 16 + lm;
                const int s = (ks * 4 + quad) ^ (r & 7);
                bf[ni] = *(const half8v*)&Bs[cur][r * 64 + s * 8];
            }
#pragma unroll
            for (int mi = 0; mi < 4; mi++)
#pragma unroll
                for (int ni = 0; ni < 4; ni++)
                    acc[mi][ni] = __builtin_amdgcn_mfma_f32_16x16x32_f16(af[mi], bf[ni], acc[mi][ni], 0, 0, 0);
        }
        asm volatile("" ::: "memory");        // reads must not sink below barrier2
        __builtin_amdgcn_s_barrier();
        asm volatile("" ::: "memory");        // restage must not hoist above barrier2
        if (it + 2 < NK) {
            const int k0n = (it + 2) * 64;
#pragma unroll
            for (int j = 0; j < 4; j++) g2l16(asrc[j] + k0n, &As[cur][aoff[j]]);
#pragma unroll
            for (int j = 0; j < 2; j++) g2l16(bsrc[j] + k0n, &Bs[cur][boff[j]]);
        }
    }

    const float gs = gsc[0];
#pragma unroll
    for (int mi = 0; mi < 4; mi++) {
#pragma unroll
        for (int r = 0; r < 4; r++) {
            const int rl = wr + mi * 16 + quad * 4 + r;
            if (mbase + rl < cnt) {
                const int pr = rows_s[rl];
#pragma unroll
                for (int ni = 0; ni < 4; ni++) {
                    const int col = nbase + wc + ni * 16 + lm;
                    float v = acc[mi][ni][r] * gs;
                    if (UP) {
                        v = fmaxf(v, 0.f);
                        v = v * v * pw_s[rl];
                        store16[(size_t)pr * N + col] = (_Float16)v;
                    } else if (store16) {
                        // atomic-free: per-pair f16 partial, summed by combine_kernel
                        store16[(size_t)pr * N + col] = (_Float16)v;
                    } else {
                        atomicAdd(&store32[(size_t)(pr >> 1) * N + col], v);
                    }
                }
            }
        }
    }
}

// ---------------- combine: out[t] = part[2t] + part[2t+1] ----------------
__global__ __launch_bounds__(256) void combine_kernel(
    const _Float16* __restrict__ part, float* __restrict__ out)
{
    const size_t i8 = ((size_t)blockIdx.x * 256 + threadIdx.x) * 8;
    const size_t t = i8 >> 11;                // / HD
    const int h = (int)(i8 & (HD - 1));
    const half8v a = *(const half8v*)&part[(t * 2) * HD + h];
    const half8v b = *(const half8v*)&part[(t * 2 + 1) * HD + h];
    float4 o0, o1;
    o0.x = (float)a[0] + (float)b[0];
    o0.y = (float)a[1] + (float)b[1];
    o0.z = (float)a[2] + (float)b[2];
    o0.w = (float)a[3] + (float)b[3];
    o1.x = (float)a[4] + (float)b[4];
    o1.y = (float)a[5] + (float)b[5];
    o1.z = (float)a[6] + (float)b[6];
    o1.w = (float)a[7] + (float)b[7];
    *(float4*)&out[i8] = o0;
    *(float4*)&out[i8 + 4] = o1;
}

// ---------------- fallback fused-dequant GEMM (round-4 structure) ----------------
template<int N, int K, bool UP>
__global__ __launch_bounds__(256) void gemm_fused_kernel(
    const _Float16* __restrict__ A, const int* __restrict__ qw,
    const float* __restrict__ bsc, const float* __restrict__ gsc,
    const int* __restrict__ counts, const int* __restrict__ pair_row,
    const float* __restrict__ pair_w,
    _Float16* __restrict__ store16, float* __restrict__ store32)
{
    constexpr int NT = N / 128;
    const int e = blockIdx.y;
    const int cnt = counts[e];
    const int mt = blockIdx.x / NT, nt = blockIdx.x % NT;
    const int mbase = mt * 128;
    if (mbase >= cnt) return;
    const int nbase = nt * 128;
    const int tid = threadIdx.x;

    __shared__ _Float16 As[128][40];
    __shared__ _Float16 Bs[128][40];
    __shared__ int rows_s[128];
    __shared__ float pw_s[128];

    if (tid < 128) {
        int idx = mbase + tid; if (idx >= cnt) idx = cnt - 1;
        rows_s[tid] = pair_row[e * CAP + idx];
        pw_s[tid] = UP ? pair_w[e * CAP + idx] : 0.f;
    }

    const int lane = tid & 63, wv = tid >> 6;
    const int quad = lane >> 4, lm = lane & 15;
    const int wr = (wv >> 1) * 64, wc = (wv & 1) * 64;

    float4v acc[4][4];
#pragma unroll
    for (int mi = 0; mi < 4; mi++)
#pragma unroll
        for (int ni = 0; ni < 4; ni++) acc[mi][ni] = (float4v){0.f, 0.f, 0.f, 0.f};

    const int am = tid & 127, akk = (tid >> 7) * 16;
    const int bn4 = (tid & 31) * 4, bkb = (tid >> 5) * 4;

    for (int k0 = 0; k0 < K; k0 += 32) {
        __syncthreads();
        {
            int pr = rows_s[am];
            const _Float16* src = A + (size_t)(UP ? (pr >> 1) : pr) * K + k0 + akk;
            *(uint4*)&As[am][akk] = *(const uint4*)src;
            *(uint4*)&As[am][akk + 8] = *(const uint4*)(src + 8);
        }
        {
            const int kabs = k0 + bkb;
            const float4 sc = *(const float4*)&bsc[((size_t)e * (K / QGROUP) + (kabs >> 4)) * N + nbase + bn4];
            const int4 c0 = *(const int4*)&qw[((size_t)e * K + kabs + 0) * N + nbase + bn4];
            const int4 c1 = *(const int4*)&qw[((size_t)e * K + kabs + 1) * N + nbase + bn4];
            const int4 c2 = *(const int4*)&qw[((size_t)e * K + kabs + 2) * N + nbase + bn4];
            const int4 c3 = *(const int4*)&qw[((size_t)e * K + kabs + 3) * N + nbase + bn4];
            half4v q;
            q[0] = (_Float16)((c0.x - 8) * sc.x); q[1] = (_Float16)((c1.x - 8) * sc.x);
            q[2] = (_Float16)((c2.x - 8) * sc.x); q[3] = (_Float16)((c3.x - 8) * sc.x);
            *(half4v*)&Bs[bn4 + 0][bkb] = q;
            q[0] = (_Float16)((c0.y - 8) * sc.y); q[1] = (_Float16)((c1.y - 8) * sc.y);
            q[2] = (_Float16)((c2.y - 8) * sc.y); q[3] = (_Float16)((c3.y - 8) * sc.y);
            *(half4v*)&Bs[bn4 + 1][bkb] = q;
            q[0] = (_Float16)((c0.z - 8) * sc.z); q[1] = (_Float16)((c1.z - 8) * sc.z);
            q[2] = (_Float16)((c2.z - 8) * sc.z); q[3] = (_Float16)((c3.z - 8) * sc.z);
            *(half4v*)&Bs[bn4 + 2][bkb] = q;
            q[0] = (_Float16)((c0.w - 8) * sc.w); q[1] = (_Float16)((c1.w - 8) * sc.w);
            q[2] = (_Float16)((c2.w - 8) * sc.w); q[3] = (_Float16)((c3.w - 8) * sc.w);
            *(half4v*)&Bs[bn4 + 3][bkb] = q;
        }
        __syncthreads();
        half8v af[4], bf[4];
#pragma unroll
        for (int mi = 0; mi < 4; mi++)
            af[mi] = *(const half8v*)&As[wr + mi * 16 + lm][quad * 8];
#pragma unroll
        for (int ni = 0; ni < 4; ni++)
            bf[ni] = *(const half8v*)&Bs[wc + ni * 16 + lm][quad * 8];
#pragma unroll
        for (int mi = 0; mi < 4; mi++)
#pragma unroll
            for (int ni = 0; ni < 4; ni++)
                acc[mi][ni] = __builtin_amdgcn_mfma_f32_16x16x32_f16(af[mi], bf[ni], acc[mi][ni], 0, 0, 0);
    }

    const float gs = gsc[0];
#pragma unroll
    for (int mi = 0; mi < 4; mi++) {
#pragma unroll
        for (int r = 0; r < 4; r++) {
            const int rl = wr + mi * 16 + quad * 4 + r;
            if (mbase + rl < cnt) {
                const int pr = rows_s[rl];
#pragma unroll
                for (int ni = 0; ni < 4; ni++) {
                    const int col = nbase + wc + ni * 16 + lm;
                    float v = acc[mi][ni][r] * gs;
                    if (UP) {
                        v = fmaxf(v, 0.f);
                        v = v * v * pw_s[rl];
                        store16[(size_t)pr * N + col] = (_Float16)v;
                    } else {
                        atomicAdd(&store32[(size_t)(pr >> 1) * N + col], v);
                    }
                }
            }
        }
    }
}

extern "C" void kernel_launch(void* const* d_in, const int* in_sizes, int n_in,
                              void* d_out, int out_size, void* d_ws, size_t ws_size,
                              hipStream_t stream) {
    const float* x   = (const float*)d_in[0];
    const float* gw  = (const float*)d_in[1];
    const float* usc = (const float*)d_in[2];
    const float* ugs = (const float*)d_in[3];
    const float* dsc = (const float*)d_in[4];
    const float* dgs = (const float*)d_in[5];
    const int*   uq  = (const int*)d_in[6];
    const int*   dq  = (const int*)d_in[7];
    float* out = (float*)d_out;

    char* ws = (char*)d_ws;
    int*   counts   = (int*)(ws + 0);
    int*   pair_row = (int*)(ws + 4096);
    float* pair_w   = (float*)(ws + 4096 + (size_t)NE * CAP * 4);        // @266240
    _Float16* xh    = (_Float16*)(ws + 528384);                          // TOK*HD f16 (16.78 MB)
    _Float16* act   = (_Float16*)(ws + 528384 + (size_t)TOK * HD * 2);   // 2*TOK*ID f16 @17.3 MB
    _Float16* wq    = (_Float16*)(ws + 528384 + (size_t)TOK * HD * 2
                                  + (size_t)2 * TOK * ID * 2);           // @34.1 MB, 67.1 MB (reused)
    // topi/topw alias the wq region (lifetime: router -> compact, before dequant writes wq)
    int*   topi = (int*)wq;
    float* topw = (float*)((char*)wq + (size_t)2 * TOK * 4);
    const size_t deq_end = 34082816ull + (size_t)NE * HD * ID * 2;       // ~101.2 MB
    const bool use_deq = ws_size >= deq_end;
    _Float16* part = (_Float16*)(ws + deq_end);                          // 2*TOK*HD f16 (33.55 MB)
    const bool use_part = use_deq && (ws_size >= deq_end + (size_t)2 * TOK * HD * 2);

    if (!use_part)
        hipMemsetAsync(out, 0, (size_t)TOK * HD * 4, stream);  // atomic paths accumulate into out

    router_kernel<<<TOK, 256, 0, stream>>>(x, gw, xh, topi, topw);
    compact_kernel<<<NE, 256, 0, stream>>>(topi, topw, counts, pair_row, pair_w);

    if (use_deq) {
        // up: K=HD=2048, N=ID=1024
        dequantT_kernel<HD, ID><<<dim3(ID / 64, HD / 64, NE), 256, 0, stream>>>(uq, usc, wq);
        gemm5_kernel<ID, HD, true><<<(CAP / 256) * (ID / 128) * NE, 512, 0, stream>>>(
            xh, wq, ugs, counts, pair_row, pair_w, act, nullptr);
        // down: K=ID=1024, N=HD=2048 (reuse wq)
        dequantT_kernel<ID, HD><<<dim3(HD / 64, ID / 64, NE), 256, 0, stream>>>(dq, dsc, wq);
        gemm5_kernel<HD, ID, false><<<(CAP / 256) * (HD / 128) * NE, 512, 0, stream>>>(
            act, wq, dgs, counts, pair_row, pair_w, use_part ? part : nullptr, out);
        if (use_part)
            combine_kernel<<<(TOK * HD) / (256 * 8), 256, 0, stream>>>(part, out);
    } else {
        gemm_fused_kernel<ID, HD, true><<<dim3((CAP / 128) * (ID / 128), NE), 256, 0, stream>>>(
            xh, uq, usc, ugs, counts, pair_row, pair_w, act, nullptr);
        gemm_fused_kernel<HD, ID, false><<<dim3((CAP / 128) * (HD / 128), NE), 256, 0, stream>>>(
            act, dq, dsc, dgs, counts, pair_row, pair_w, nullptr, out);
    }
}

// Round 8
// 522.396 us; speedup vs baseline: 1.1092x; 1.1092x over previous
//
#include <hip/hip_runtime.h>

#define TOK 4096
#define NE 16
#define HD 2048
#define ID 1024
#define QGROUP 16
#define CAP 4096

typedef _Float16 half4v __attribute__((ext_vector_type(4)));
typedef _Float16 half8v __attribute__((ext_vector_type(8)));
typedef float float4v __attribute__((ext_vector_type(4)));

__device__ __forceinline__ void g2l16(const void* g, void* l) {
    __builtin_amdgcn_global_load_lds(
        (const __attribute__((address_space(1))) unsigned int*)g,
        (__attribute__((address_space(3))) unsigned int*)l, 16, 0, 0);
}

// ---------------- router: per-token top2 + fused f32->f16 conversion of x ----------------
__global__ __launch_bounds__(256) void router_kernel(
    const float* __restrict__ x, const float* __restrict__ gw,
    _Float16* __restrict__ xh, int* __restrict__ topi, float* __restrict__ topw)
{
    const int t = blockIdx.x;
    const int tid = threadIdx.x;
    const int h8 = tid * 8;
    const float* xr = x + (size_t)t * HD;
    const float4 f0 = *(const float4*)&xr[h8];
    const float4 f1 = *(const float4*)&xr[h8 + 4];
    half8v hv;
    hv[0] = (_Float16)f0.x; hv[1] = (_Float16)f0.y; hv[2] = (_Float16)f0.z; hv[3] = (_Float16)f0.w;
    hv[4] = (_Float16)f1.x; hv[5] = (_Float16)f1.y; hv[6] = (_Float16)f1.z; hv[7] = (_Float16)f1.w;
    *(half8v*)&xh[(size_t)t * HD + h8] = hv;

    float p[NE];
#pragma unroll
    for (int e = 0; e < NE; e++) {
        const float4 g0 = *(const float4*)&gw[e * HD + h8];
        const float4 g1 = *(const float4*)&gw[e * HD + h8 + 4];
        p[e] = f0.x * g0.x + f0.y * g0.y + f0.z * g0.z + f0.w * g0.w
             + f1.x * g1.x + f1.y * g1.y + f1.z * g1.z + f1.w * g1.w;
    }
#pragma unroll
    for (int off = 32; off > 0; off >>= 1) {
#pragma unroll
        for (int e = 0; e < NE; e++) p[e] += __shfl_down(p[e], off, 64);
    }
    __shared__ float part[4][NE];
    int wave = tid >> 6, lane = tid & 63;
    if (lane == 0) {
#pragma unroll
        for (int e = 0; e < NE; e++) part[wave][e] = p[e];
    }
    __syncthreads();
    if (tid == 0) {
        float s[NE]; float sum = 0.f;
#pragma unroll
        for (int e = 0; e < NE; e++) {
            float l = part[0][e] + part[1][e] + part[2][e] + part[3][e];
            float sg = 1.f / (1.f + expf(-l));
            s[e] = sg; sum += sg;
        }
        int i1 = 0;
#pragma unroll
        for (int e = 1; e < NE; e++) if (s[e] > s[i1]) i1 = e;
        int i2 = (i1 == 0) ? 1 : 0;
#pragma unroll
        for (int e = 0; e < NE; e++) if (e != i1 && s[e] > s[i2]) i2 = e;
        float p1 = s[i1] / sum, p2 = s[i2] / sum;
        float inv = 1.f / (p1 + p2 + 1e-20f);
        topi[t * 2 + 0] = i1; topw[t * 2 + 0] = p1 * inv;
        topi[t * 2 + 1] = i2; topw[t * 2 + 1] = p2 * inv;
    }
}

// ---------------- compaction: one block per expert, deterministic ordered scan ----------------
__global__ __launch_bounds__(256) void compact_kernel(
    const int* __restrict__ topi, const float* __restrict__ topw,
    int* __restrict__ counts, int* __restrict__ pair_row, float* __restrict__ pair_w)
{
    const int e = blockIdx.x;
    const int tid = threadIdx.x;
    const int lane = tid & 63, wv = tid >> 6;
    __shared__ int wsum[4];
    int running = 0;
    for (int base = 0; base < 2 * TOK; base += 256) {
        const int idx = base + tid;
        const bool f = (topi[idx] == e);
        unsigned long long b = __ballot(f);
        int pre = __popcll(b & ((1ull << lane) - 1ull));
        if (lane == 0) wsum[wv] = __popcll(b);
        __syncthreads();
        int woff = 0;
#pragma unroll
        for (int w = 0; w < 4; w++) if (w < wv) woff += wsum[w];
        const int tot = wsum[0] + wsum[1] + wsum[2] + wsum[3];
        if (f) {
            const int pos = running + woff + pre;
            pair_row[e * CAP + pos] = idx;          // pair id = t*2+slot
            pair_w[e * CAP + pos] = topw[idx];
        }
        running += tot;
        __syncthreads();
    }
    if (tid == 0) counts[e] = running;
}

// ---------------- dequant + transpose: codes [E][K][N] int32 -> f16 [E][N][K] ----------------
// LDS tile stride = 70 f16 (35 dwords, odd): transpose-read k-term 35*k mod 32 = {0,16} over
// kseg in {0,16,32,48} -> 2-way (free), vs stride 68 (34 dw, always 0 -> 8-way conflict).
// Writes are 2x u32 (odd-dword stride makes 8B stores misaligned on odd rows; 4B is aligned).
template<int K, int N>
__global__ __launch_bounds__(256) void dequantT_kernel(
    const int* __restrict__ qw, const float* __restrict__ bsc, _Float16* __restrict__ wq)
{
    const int e = blockIdx.z, kt = blockIdx.y, nt = blockIdx.x;
    const int tid = threadIdx.x;
    __shared__ _Float16 T[64][70];   // [k][n]

    const int c4 = (tid & 15) * 4;
    const int r0 = tid >> 4;         // 0..15
#pragma unroll
    for (int p = 0; p < 4; p++) {
        const int r = p * 16 + r0;
        const int kabs = kt * 64 + r;
        const int4 c = *(const int4*)&qw[((size_t)e * K + kabs) * N + nt * 64 + c4];
        const float4 sc = *(const float4*)&bsc[((size_t)e * (K / QGROUP) + (kabs >> 4)) * N + nt * 64 + c4];
        union { _Float16 h[4]; unsigned u[2]; } cv;
        cv.h[0] = (_Float16)((float)(c.x - 8) * sc.x);
        cv.h[1] = (_Float16)((float)(c.y - 8) * sc.y);
        cv.h[2] = (_Float16)((float)(c.z - 8) * sc.z);
        cv.h[3] = (_Float16)((float)(c.w - 8) * sc.w);
        *(unsigned*)&T[r][c4]     = cv.u[0];
        *(unsigned*)&T[r][c4 + 2] = cv.u[1];
    }
    __syncthreads();
    const int nrow = tid >> 2;
    const int kseg = (tid & 3) * 16;
    half8v o0, o1;
#pragma unroll
    for (int i = 0; i < 8; i++) o0[i] = T[kseg + i][nrow];
#pragma unroll
    for (int i = 0; i < 8; i++) o1[i] = T[kseg + 8 + i][nrow];
    _Float16* dst = wq + ((size_t)e * N + nt * 64 + nrow) * K + kt * 64 + kseg;
    *(half8v*)dst = o0;
    *(half8v*)(dst + 8) = o1;
}

// ---------------- gemm5: 128M x 128N x BK=64, XOR-swizzled LDS (round-5 measured-best) ----------------
// Tile ladder measured on this structure: 64x128(3blk)~77 / 128x128(2blk)=BEST / 256x128(1blk)=107us.
// Occupancy >=2 blocks/CU is the binding constraint (cross-block TLP covers load latency); feed-byte
// optimization below that threshold regresses (round-7 lesson).
// 4 waves as 2x2, each wave 64x64 (acc 4x4). LDS 65.5 KB -> 2 blocks/CU.
// Counted-vmcnt DOUBLE buffer (round-3-verified fence discipline), 8 g2l16/thread/tile:
//   prologue: stage(0->buf0), stage(1->buf1)         [16 loads outstanding]
//   iter it:  s_waitcnt vmcnt(8)  <- tile it landed, tile it+1 flying (vmcnt(0) only at last)
//             s_barrier ; [fence] ; ds_read+MFMA on buf[it&1] ; [fence] ; s_barrier ; [fence]
//             stage(it+2 -> buf[it&1])               [back to 16 outstanding]
// Fences REQUIRED: LLVM models s_barrier as IntrNoMem; without them restage/ds_reads cross
// the raw barrier -> inter-wave WAR race on buf[cur] (round-2 failure mode).
// NEW (round-8): MFMA operands SWAPPED: acc = mfma(bf, af). Result mapping is a fixed function
// of operand position (relabeling grounded in the passing round-5 epilogue): M-index -> lane&15,
// N-index -> (lane>>4)*4+reg. Each lane then owns ONE output row and 4 CONSECUTIVE columns per
// reg quad -> epilogue stores become 8B half4v (4x fewer store instructions), pw/rows read 1x/mi.
template<int N, int K, bool UP>
__global__ __launch_bounds__(256, 2) void gemm5_kernel(
    const _Float16* __restrict__ A, const _Float16* __restrict__ BT,
    const float* __restrict__ gsc,
    const int* __restrict__ counts, const int* __restrict__ pair_row,
    const float* __restrict__ pair_w,
    _Float16* __restrict__ store16, float* __restrict__ store32)
{
    constexpr int NT = N / 128;
    constexpr int MT = CAP / 128;
    constexpr int NK = K / 64;
    const int bx = blockIdx.x;
    const int g8 = bx & 7;                    // XCD hint
    const int rest = bx >> 3;
    const int m = rest % MT;
    const int g = (rest / MT) * 8 + g8;       // (NT*NE) multiple of 8
    const int e = g / NT, nt = g % NT;
    const int cnt = counts[e];
    const int mbase = m * 128;
    if (mbase >= cnt) return;
    const int nbase = nt * 128;
    const int tid = threadIdx.x;

    __shared__ _Float16 As[2][128 * 64];      // 2 x 16 KB
    __shared__ _Float16 Bs[2][128 * 64];      // 2 x 16 KB
    __shared__ int rows_s[128];
    __shared__ float pw_s[128];

    if (tid < 128) {
        int idx = mbase + tid; if (idx >= cnt) idx = cnt - 1;
        rows_s[tid] = pair_row[e * CAP + idx];
        pw_s[tid] = UP ? pair_w[e * CAP + idx] : 0.f;
    }
    __syncthreads();

    // staging maps (granule = 16 B = 8 f16). A: 1024 granules (4/thread), B: 1024 (4/thread).
    const _Float16* asrc[4]; int aoff[4];
#pragma unroll
    for (int j = 0; j < 4; j++) {
        const int gidx = j * 256 + tid;
        const int r = gidx >> 3, s = gidx & 7, c = s ^ (r & 7);
        const int pr = rows_s[r];
        asrc[j] = A + (size_t)(UP ? (pr >> 1) : pr) * K + c * 8;
        aoff[j] = r * 64 + s * 8;
    }
    const _Float16* bsrc[4]; int boff[4];
#pragma unroll
    for (int j = 0; j < 4; j++) {
        const int gidx = j * 256 + tid;
        const int r = gidx >> 3, s = gidx & 7, c = s ^ (r & 7);
        bsrc[j] = BT + ((size_t)e * N + nbase + r) * K + c * 8;
        boff[j] = r * 64 + s * 8;
    }

    const int lane = tid & 63, wv = tid >> 6;
    const int quad = lane >> 4, lm = lane & 15;
    const int wr = (wv >> 1) * 64, wc = (wv & 1) * 64;

    float4v acc[4][4];
#pragma unroll
    for (int mi = 0; mi < 4; mi++)
#pragma unroll
        for (int ni = 0; ni < 4; ni++) acc[mi][ni] = (float4v){0.f, 0.f, 0.f, 0.f};

    // prologue: stage tile 0 -> buf0, tile 1 -> buf1 (16 loads in flight)
#pragma unroll
    for (int j = 0; j < 4; j++) g2l16(asrc[j], &As[0][aoff[j]]);
#pragma unroll
    for (int j = 0; j < 4; j++) g2l16(bsrc[j], &Bs[0][boff[j]]);
#pragma unroll
    for (int j = 0; j < 4; j++) g2l16(asrc[j] + 64, &As[1][aoff[j]]);
#pragma unroll
    for (int j = 0; j < 4; j++) g2l16(bsrc[j] + 64, &Bs[1][boff[j]]);

    for (int it = 0; it < NK; ++it) {
        if (it + 1 < NK) {
            asm volatile("s_waitcnt vmcnt(8)" ::: "memory");   // tile it landed; it+1 in flight
        } else {
            asm volatile("s_waitcnt vmcnt(0)" ::: "memory");   // last tile: only its 8 remain
        }
        __builtin_amdgcn_s_barrier();
        asm volatile("" ::: "memory");        // reads must not hoist above barrier1
        const int cur = it & 1;
#pragma unroll
        for (int ks = 0; ks < 2; ks++) {
            half8v af[4], bf[4];
#pragma unroll
            for (int mi = 0; mi < 4; mi++) {
                const int r = wr + mi * 16 + lm;
                const int s = (ks * 4 + quad) ^ (r & 7);
                af[mi] = *(const half8v*)&As[cur][r * 64 + s * 8];
            }
#pragma unroll
            for (int ni = 0; ni < 4; ni++) {
                const int r = wc + ni * 16 + lm;
                const int s = (ks * 4 + quad) ^ (r & 7);
                bf[ni] = *(const half8v*)&Bs[cur][r * 64 + s * 8];
            }
#pragma unroll
            for (int mi = 0; mi < 4; mi++)
#pragma unroll
                for (int ni = 0; ni < 4; ni++)
                    acc[mi][ni] = __builtin_amdgcn_mfma_f32_16x16x32_f16(bf[ni], af[mi], acc[mi][ni], 0, 0, 0);
        }
        asm volatile("" ::: "memory");        // reads must not sink below barrier2
        __builtin_amdgcn_s_barrier();
        asm volatile("" ::: "memory");        // restage must not hoist above barrier2
        if (it + 2 < NK) {
            const int k0n = (it + 2) * 64;
#pragma unroll
            for (int j = 0; j < 4; j++) g2l16(asrc[j] + k0n, &As[cur][aoff[j]]);
#pragma unroll
            for (int j = 0; j < 4; j++) g2l16(bsrc[j] + k0n, &Bs[cur][boff[j]]);
        }
    }

    // Epilogue (swapped-operand layout): lane owns row rl = wr+mi*16+lm; regs give 4 consecutive
    // cols at nbase+wc+ni*16+quad*4. 8B vectorized stores.
    const float gs = gsc[0];
#pragma unroll
    for (int mi = 0; mi < 4; mi++) {
        const int rl = wr + mi * 16 + lm;
        if (mbase + rl < cnt) {
            const int pr = rows_s[rl];
            const float pw = pw_s[rl];
#pragma unroll
            for (int ni = 0; ni < 4; ni++) {
                const int col = nbase + wc + ni * 16 + quad * 4;
                if (UP) {
                    half4v h;
#pragma unroll
                    for (int r = 0; r < 4; r++) {
                        float v = fmaxf(acc[mi][ni][r] * gs, 0.f);
                        h[r] = (_Float16)(v * v * pw);
                    }
                    *(half4v*)&store16[(size_t)pr * N + col] = h;
                } else if (store16) {
                    half4v h;
#pragma unroll
                    for (int r = 0; r < 4; r++) h[r] = (_Float16)(acc[mi][ni][r] * gs);
                    *(half4v*)&store16[(size_t)pr * N + col] = h;
                } else {
#pragma unroll
                    for (int r = 0; r < 4; r++)
                        atomicAdd(&store32[(size_t)(pr >> 1) * N + col + r], acc[mi][ni][r] * gs);
                }
            }
        }
    }
}

// ---------------- combine: out[t] = part[2t] + part[2t+1] ----------------
__global__ __launch_bounds__(256) void combine_kernel(
    const _Float16* __restrict__ part, float* __restrict__ out)
{
    const size_t i8 = ((size_t)blockIdx.x * 256 + threadIdx.x) * 8;
    const size_t t = i8 >> 11;                // / HD
    const int h = (int)(i8 & (HD - 1));
    const half8v a = *(const half8v*)&part[(t * 2) * HD + h];
    const half8v b = *(const half8v*)&part[(t * 2 + 1) * HD + h];
    float4 o0, o1;
    o0.x = (float)a[0] + (float)b[0];
    o0.y = (float)a[1] + (float)b[1];
    o0.z = (float)a[2] + (float)b[2];
    o0.w = (float)a[3] + (float)b[3];
    o1.x = (float)a[4] + (float)b[4];
    o1.y = (float)a[5] + (float)b[5];
    o1.z = (float)a[6] + (float)b[6];
    o1.w = (float)a[7] + (float)b[7];
    *(float4*)&out[i8] = o0;
    *(float4*)&out[i8 + 4] = o1;
}

// ---------------- fallback fused-dequant GEMM ----------------
template<int N, int K, bool UP>
__global__ __launch_bounds__(256) void gemm_fused_kernel(
    const _Float16* __restrict__ A, const int* __restrict__ qw,
    const float* __restrict__ bsc, const float* __restrict__ gsc,
    const int* __restrict__ counts, const int* __restrict__ pair_row,
    const float* __restrict__ pair_w,
    _Float16* __restrict__ store16, float* __restrict__ store32)
{
    constexpr int NT = N / 128;
    const int e = blockIdx.y;
    const int cnt = counts[e];
    const int mt = blockIdx.x / NT, nt = blockIdx.x % NT;
    const int mbase = mt * 128;
    if (mbase >= cnt) return;
    const int nbase = nt * 128;
    const int tid = threadIdx.x;

    __shared__ _Float16 As[128][40];
    __shared__ _Float16 Bs[128][40];
    __shared__ int rows_s[128];
    __shared__ float pw_s[128];

    if (tid < 128) {
        int idx = mbase + tid; if (idx >= cnt) idx = cnt - 1;
        rows_s[tid] = pair_row[e * CAP + idx];
        pw_s[tid] = UP ? pair_w[e * CAP + idx] : 0.f;
    }

    const int lane = tid & 63, wv = tid >> 6;
    const int quad = lane >> 4, lm = lane & 15;
    const int wr = (wv >> 1) * 64, wc = (wv & 1) * 64;

    float4v acc[4][4];
#pragma unroll
    for (int mi = 0; mi < 4; mi++)
#pragma unroll
        for (int ni = 0; ni < 4; ni++) acc[mi][ni] = (float4v){0.f, 0.f, 0.f, 0.f};

    const int am = tid & 127, akk = (tid >> 7) * 16;
    const int bn4 = (tid & 31) * 4, bkb = (tid >> 5) * 4;

    for (int k0 = 0; k0 < K; k0 += 32) {
        __syncthreads();
        {
            int pr = rows_s[am];
            const _Float16* src = A + (size_t)(UP ? (pr >> 1) : pr) * K + k0 + akk;
            *(uint4*)&As[am][akk] = *(const uint4*)src;
            *(uint4*)&As[am][akk + 8] = *(const uint4*)(src + 8);
        }
        {
            const int kabs = k0 + bkb;
            const float4 sc = *(const float4*)&bsc[((size_t)e * (K / QGROUP) + (kabs >> 4)) * N + nbase + bn4];
            const int4 c0 = *(const int4*)&qw[((size_t)e * K + kabs + 0) * N + nbase + bn4];
            const int4 c1 = *(const int4*)&qw[((size_t)e * K + kabs + 1) * N + nbase + bn4];
            const int4 c2 = *(const int4*)&qw[((size_t)e * K + kabs + 2) * N + nbase + bn4];
            const int4 c3 = *(const int4*)&qw[((size_t)e * K + kabs + 3) * N + nbase + bn4];
            half4v q;
            q[0] = (_Float16)((c0.x - 8) * sc.x); q[1] = (_Float16)((c1.x - 8) * sc.x);
            q[2] = (_Float16)((c2.x - 8) * sc.x); q[3] = (_Float16)((c3.x - 8) * sc.x);
            *(half4v*)&Bs[bn4 + 0][bkb] = q;
            q[0] = (_Float16)((c0.y - 8) * sc.y); q[1] = (_Float16)((c1.y - 8) * sc.y);
            q[2] = (_Float16)((c2.y - 8) * sc.y); q[3] = (_Float16)((c3.y - 8) * sc.y);
            *(half4v*)&Bs[bn4 + 1][bkb] = q;
            q[0] = (_Float16)((c0.z - 8) * sc.z); q[1] = (_Float16)((c1.z - 8) * sc.z);
            q[2] = (_Float16)((c2.z - 8) * sc.z); q[3] = (_Float16)((c3.z - 8) * sc.z);
            *(half4v*)&Bs[bn4 + 2][bkb] = q;
            q[0] = (_Float16)((c0.w - 8) * sc.w); q[1] = (_Float16)((c1.w - 8) * sc.w);
            q[2] = (_Float16)((c2.w - 8) * sc.w); q[3] = (_Float16)((c3.w - 8) * sc.w);
            *(half4v*)&Bs[bn4 + 3][bkb] = q;
        }
        __syncthreads();
        half8v af[4], bf[4];
#pragma unroll
        for (int mi = 0; mi < 4; mi++)
            af[mi] = *(const half8v*)&As[wr + mi * 16 + lm][quad * 8];
#pragma unroll
        for (int ni = 0; ni < 4; ni++)
            bf[ni] = *(const half8v*)&Bs[wc + ni * 16 + lm][quad * 8];
#pragma unroll
        for (int mi = 0; mi < 4; mi++)
#pragma unroll
            for (int ni = 0; ni < 4; ni++)
                acc[mi][ni] = __builtin_amdgcn_mfma_f32_16x16x32_f16(af[mi], bf[ni], acc[mi][ni], 0, 0, 0);
    }

    const float gs = gsc[0];
#pragma unroll
    for (int mi = 0; mi < 4; mi++) {
#pragma unroll
        for (int r = 0; r < 4; r++) {
            const int rl = wr + mi * 16 + quad * 4 + r;
            if (mbase + rl < cnt) {
                const int pr = rows_s[rl];
#pragma unroll
                for (int ni = 0; ni < 4; ni++) {
                    const int col = nbase + wc + ni * 16 + lm;
                    float v = acc[mi][ni][r] * gs;
                    if (UP) {
                        v = fmaxf(v, 0.f);
                        v = v * v * pw_s[rl];
                        store16[(size_t)pr * N + col] = (_Float16)v;
                    } else {
                        atomicAdd(&store32[(size_t)(pr >> 1) * N + col], v);
                    }
                }
            }
        }
    }
}

extern "C" void kernel_launch(void* const* d_in, const int* in_sizes, int n_in,
                              void* d_out, int out_size, void* d_ws, size_t ws_size,
                              hipStream_t stream) {
    const float* x   = (const float*)d_in[0];
    const float* gw  = (const float*)d_in[1];
    const float* usc = (const float*)d_in[2];
    const float* ugs = (const float*)d_in[3];
    const float* dsc = (const float*)d_in[4];
    const float* dgs = (const float*)d_in[5];
    const int*   uq  = (const int*)d_in[6];
    const int*   dq  = (const int*)d_in[7];
    float* out = (float*)d_out;

    char* ws = (char*)d_ws;
    int*   counts   = (int*)(ws + 0);
    int*   pair_row = (int*)(ws + 4096);
    float* pair_w   = (float*)(ws + 4096 + (size_t)NE * CAP * 4);        // @266240
    _Float16* xh    = (_Float16*)(ws + 528384);                          // TOK*HD f16 (16.78 MB)
    _Float16* act   = (_Float16*)(ws + 528384 + (size_t)TOK * HD * 2);   // 2*TOK*ID f16 @17.3 MB
    _Float16* wq    = (_Float16*)(ws + 528384 + (size_t)TOK * HD * 2
                                  + (size_t)2 * TOK * ID * 2);           // @34.1 MB, 67.1 MB (reused)
    // topi/topw alias the wq region (lifetime: router -> compact, before dequant writes wq)
    int*   topi = (int*)wq;
    float* topw = (float*)((char*)wq + (size_t)2 * TOK * 4);
    const size_t deq_end = 34082816ull + (size_t)NE * HD * ID * 2;       // ~101.2 MB
    const bool use_deq = ws_size >= deq_end;
    _Float16* part = (_Float16*)(ws + deq_end);                          // 2*TOK*HD f16 (33.55 MB)
    const bool use_part = use_deq && (ws_size >= deq_end + (size_t)2 * TOK * HD * 2);

    if (!use_part)
        hipMemsetAsync(out, 0, (size_t)TOK * HD * 4, stream);  // atomic paths accumulate into out

    router_kernel<<<TOK, 256, 0, stream>>>(x, gw, xh, topi, topw);
    compact_kernel<<<NE, 256, 0, stream>>>(topi, topw, counts, pair_row, pair_w);

    if (use_deq) {
        // up: K=HD=2048, N=ID=1024
        dequantT_kernel<HD, ID><<<dim3(ID / 64, HD / 64, NE), 256, 0, stream>>>(uq, usc, wq);
        gemm5_kernel<ID, HD, true><<<(CAP / 128) * (ID / 128) * NE, 256, 0, stream>>>(
            xh, wq, ugs, counts, pair_row, pair_w, act, nullptr);
        // down: K=ID=1024, N=HD=2048 (reuse wq)
        dequantT_kernel<ID, HD><<<dim3(HD / 64, ID / 64, NE), 256, 0, stream>>>(dq, dsc, wq);
        gemm5_kernel<HD, ID, false><<<(CAP / 128) * (HD / 128) * NE, 256, 0, stream>>>(
            act, wq, dgs, counts, pair_row, pair_w, use_part ? part : nullptr, out);
        if (use_part)
            combine_kernel<<<(TOK * HD) / (256 * 8), 256, 0, stream>>>(part, out);
    } else {
        gemm_fused_kernel<ID, HD, true><<<dim3((CAP / 128) * (ID / 128), NE), 256, 0, stream>>>(
            xh, uq, usc, ugs, counts, pair_row, pair_w, act, nullptr);
        gemm_fused_kernel<HD, ID, false><<<dim3((CAP / 128) * (HD / 128), NE), 256, 0, stream>>>(
            act, dq, dsc, dgs, counts, pair_row, pair_w, nullptr, out);
    }
}